// Round 1
// baseline (491.346 us; speedup 1.0000x reference)
//
#include <hip/hip_runtime.h>
#include <hip/hip_bf16.h>
#include <math.h>

// ArcFace loss, MI355X. B=2048, D=512, C=32768.
// R10: R9 structure, but the GEMM inner loop now uses the MX-scaled
// mfma_scale_f32_16x16x128_f8f6f4 with unit scales (E8M0 0x7F = 2^0),
// which runs at 2x the non-scaled fp8 rate (4661 vs 2047 TF measured).
// Unit scales make it bit-equivalent per-product to the R9 fp8 MFMA.
// Even K-64 slab: stash the 8 longx2 fragments in registers; odd slab:
// read its 8 fragments, concatenate to 32B operands ({even|odd} order,
// identical for A and B so the k-permutation cancels), issue 16 K=128
// MFMAs. Staging, swizzle, barriers, epilogue unchanged from R9
// (absmax 0.0, conflicts 0, FETCH 12MB via XCD swizzle).

#define BN 2048
#define DK 512
#define CN 32768

typedef __attribute__((ext_vector_type(4))) float floatx4;
typedef __attribute__((ext_vector_type(2))) long longx2;
typedef __attribute__((ext_vector_type(4))) long longx4;
typedef __attribute__((ext_vector_type(8))) int intx8;

__device__ inline float dot4(floatx4 a, floatx4 b) {
  return a.x * b.x + a.y * b.y + a.z * b.z + a.w * b.w;
}

__device__ inline int pack_fp8x4(floatx4 v) {
  int r = __builtin_amdgcn_cvt_pk_fp8_f32(v.x, v.y, 0, false);
  r = __builtin_amdgcn_cvt_pk_fp8_f32(v.z, v.w, r, true);
  return r;
}

// dword j (0..15) of a 64B slab -> MFMA-ready position:
// q=(j>>1)&3 (8B piece), p=j>>3 (k-step), dest = q*4 + p*2 + (j&1)
__device__ inline int permute16(int j) {
  return ((j >> 1) & 3) * 4 + (j >> 3) * 2 + (j & 1);
}

__device__ inline void async_ld16(const void* g, void* l) {
  __builtin_amdgcn_global_load_lds(
      (const __attribute__((address_space(1))) void*)g,
      (__attribute__((address_space(3))) void*)l, 16, 0, 0);
}

// ---- kernel 1: fused prep -> fp8 rows (512 B each), MFMA-ready byte order.
__global__ void prep_kernel(const float* __restrict__ feat,
                            const int* __restrict__ y,
                            const float* __restrict__ w,
                            int* __restrict__ fb8,     // [BN][128] dwords
                            int* __restrict__ wb8,     // [CN][128] dwords
                            float* __restrict__ tgt,
                            float* __restrict__ rowsum) {
  const int wave = threadIdx.x >> 6;
  const int l = threadIdx.x & 63;
  const int d0 = ((l >> 4) * 16)       + permute16(l & 15);
  const int d1 = ((4 + (l >> 4)) * 16) + permute16(l & 15);
  if (blockIdx.x < 8192) {
    const int row = blockIdx.x * 4 + wave;
    const floatx4* src = (const floatx4*)(w + (size_t)row * DK);
    floatx4 v0 = src[l];
    floatx4 v1 = src[64 + l];
    float s = dot4(v0, v0) + dot4(v1, v1);
#pragma unroll
    for (int off = 1; off < 64; off <<= 1) s += __shfl_xor(s, off, 64);
    const float scale = 1.0f / fmaxf(sqrtf(s), 1e-12f);
    v0 *= scale; v1 *= scale;
    int* db = wb8 + (size_t)row * 128;
    db[d0] = pack_fp8x4(v0);
    db[d1] = pack_fp8x4(v1);
  } else {
    const int i = (blockIdx.x - 8192) * 4 + wave;
    const floatx4* src = (const floatx4*)(feat + (size_t)i * DK);
    floatx4 v0 = src[l];
    floatx4 v1 = src[64 + l];
    const int cls = y[i];
    const floatx4* wr = (const floatx4*)(w + (size_t)cls * DK);
    floatx4 w0 = wr[l], w1 = wr[64 + l];
    float s  = dot4(v0, v0) + dot4(v1, v1);
    float d  = dot4(v0, w0) + dot4(v1, w1);
    float wn = dot4(w0, w0) + dot4(w1, w1);
#pragma unroll
    for (int off = 1; off < 64; off <<= 1) {
      s  += __shfl_xor(s, off, 64);
      d  += __shfl_xor(d, off, 64);
      wn += __shfl_xor(wn, off, 64);
    }
    const float fscale = 1.0f / fmaxf(sqrtf(s), 1e-12f);
    v0 *= fscale; v1 *= fscale;
    int* db = fb8 + (size_t)i * 128;
    db[d0] = pack_fp8x4(v0);
    db[d1] = pack_fp8x4(v1);
    if (l == 0) {
      tgt[i] = d * fscale / fmaxf(sqrtf(wn), 1e-12f);
      rowsum[i] = 0.0f;
    }
  }
}

// ---- kernel 2: 128(M)x256(N) MX-fp8 MFMA GEMM (16x16x128, unit scales),
// ping-pong LDS, one barrier per K-64 slab, fused exp row-sum.
__launch_bounds__(512, 4)
__global__ void gemm_exp_kernel(const char* __restrict__ fb8,   // [BN][512] B
                                const char* __restrict__ wb8,   // [CN][512] B
                                float* __restrict__ rowsum) {
  __shared__ char As[2][128 * 64];   // 2 x  8 KB
  __shared__ char Bs[2][256 * 64];   // 2 x 16 KB
  __shared__ float lsum[128];

  const int tid  = threadIdx.x;
  const int wave = tid >> 6;
  const int lane = tid & 63;

  // XCD swizzle: n -> (x: M-tile 0..15, y: N-tile 0..127); XCD(n%8) owns y%8.
  const int n = blockIdx.x;
  const int tileM = ((n >> 3) & 15) * 128;
  const int tileN = (((n >> 7) << 3) | (n & 7)) * 256;

  const int wm = (wave >> 2) * 64;  // wave M offset (0 or 64)
  const int wn = (wave & 3) * 64;   // wave N offset (0..192)

  if (tid < 128) lsum[tid] = 0.0f;  // covered by first K-loop barrier

  floatx4 acc[4][4];
#pragma unroll
  for (int mi = 0; mi < 4; ++mi)
#pragma unroll
    for (int ni = 0; ni < 4; ++ni)
      acc[mi][ni] = (floatx4){0.f, 0.f, 0.f, 0.f};

  // staging (unchanged): unit c -> row c>>2, stored pos c&3;
  // fetch global unit (c&3)^((row>>1)&3).
  const int mA = tid >> 2;
  const int uA = (tid & 3) ^ ((mA >> 1) & 3);
  const int mB1 = (512 + tid) >> 2;
  const int uB1 = (tid & 3) ^ ((mB1 >> 1) & 3);
  const char* gA  = fb8 + (size_t)(tileM + mA)  * DK + uA  * 16;
  const char* gB0 = wb8 + (size_t)(tileN + mA)  * DK + uA  * 16;   // rows 0..127
  const char* gB1 = wb8 + (size_t)(tileN + mB1) * DK + uB1 * 16;   // rows 128..255
  const int ldsA  = wave * 1024;         // wave-uniform LDS offsets
  const int ldsB0 = wave * 1024;
  const int ldsB1 = 8192 + wave * 1024;

  // hoisted fragment LDS byte-offsets (loop-invariant)
  const int mrow = lane & 15;
  const int q    = lane >> 4;
  int offA[4], offB[4];
#pragma unroll
  for (int mi = 0; mi < 4; ++mi) {
    const int row = wm + mi * 16 + mrow;
    offA[mi] = row * 64 + (q ^ ((row >> 1) & 3)) * 16;
  }
#pragma unroll
  for (int ni = 0; ni < 4; ++ni) {
    const int row = wn + ni * 16 + mrow;
    offB[ni] = row * 64 + (q ^ ((row >> 1) & 3)) * 16;
  }

  // prologue: stage slab 0 into buffer 0
  async_ld16(gA,  &As[0][ldsA]);
  async_ld16(gB0, &Bs[0][ldsB0]);
  async_ld16(gB1, &Bs[0][ldsB1]);
  gA += 64; gB0 += 64; gB1 += 64;

  // even slab: stash fragments; odd slab: concatenate -> 16 K=128 MFMAs.
  longx2 aL[4], bL[4];
#pragma unroll
  for (int kk = 0; kk < DK / 64; ++kk) {
    const int cur = kk & 1;
    // Barrier: (a) drains this wave's vmcnt -> buf[cur] resident (its loads
    // were issued one full iteration ago); (b) all waves done with buf[cur^1].
    __syncthreads();
    if (kk < DK / 64 - 1) {
      const int nxt = cur ^ 1;
      async_ld16(gA,  &As[nxt][ldsA]);
      async_ld16(gB0, &Bs[nxt][ldsB0]);
      async_ld16(gB1, &Bs[nxt][ldsB1]);
      gA += 64; gB0 += 64; gB1 += 64;
    }

    const char* Ab = As[cur];
    const char* Bb = Bs[cur];
    if ((kk & 1) == 0) {
      // K-128 low half: keep fragments in registers across the barrier-free
      // register carry into the next (odd) slab.
#pragma unroll
      for (int mi = 0; mi < 4; ++mi) aL[mi] = *(const longx2*)(Ab + offA[mi]);
#pragma unroll
      for (int ni = 0; ni < 4; ++ni) bL[ni] = *(const longx2*)(Bb + offB[ni]);
    } else {
      longx4 a4[4], b4[4];
#pragma unroll
      for (int mi = 0; mi < 4; ++mi) {
        longx2 t = *(const longx2*)(Ab + offA[mi]);
        a4[mi] = (longx4){aL[mi].x, aL[mi].y, t.x, t.y};
      }
#pragma unroll
      for (int ni = 0; ni < 4; ++ni) {
        longx2 t = *(const longx2*)(Bb + offB[ni]);
        b4[ni] = (longx4){bL[ni].x, bL[ni].y, t.x, t.y};
      }
      // 16 MX-scaled MFMAs, K=128, unit scales (0x7F = 2^0): products are
      // identical to the fp8_fp8 path; A/B use the same {even|odd} byte
      // order so the k-permutation cancels in the contraction.
#pragma unroll
      for (int mi = 0; mi < 4; ++mi)
#pragma unroll
        for (int ni = 0; ni < 4; ++ni)
          acc[mi][ni] = __builtin_amdgcn_mfma_scale_f32_16x16x128_f8f6f4(
              (intx8)a4[mi], (intx8)b4[ni], acc[mi][ni],
              0, 0, 0, 0x7f7f7f7f, 0, 0x7f7f7f7f);
    }
  }

  // epilogue: rowsum[m] += sum_n exp(64 * wf[m][n])
  const int rowq = (lane >> 4) * 4;  // C/D layout: row = quad*4 + reg
#pragma unroll
  for (int mi = 0; mi < 4; ++mi) {
#pragma unroll
    for (int r = 0; r < 4; ++r) {
      float v = 0.f;
#pragma unroll
      for (int ni = 0; ni < 4; ++ni)
        v += __expf(64.0f * acc[mi][ni][r]);
      v += __shfl_xor(v, 1, 64);
      v += __shfl_xor(v, 2, 64);
      v += __shfl_xor(v, 4, 64);
      v += __shfl_xor(v, 8, 64);
      if ((lane & 15) == 0)
        atomicAdd(&lsum[wm + mi * 16 + rowq + r], v);
    }
  }
  __syncthreads();
  if (tid < 128)
    atomicAdd(&rowsum[tileM + tid], lsum[tid]);
}

// ---- kernel 3: final loss
__global__ void loss_kernel(const float* __restrict__ tgt,
                            const float* __restrict__ rowsum,
                            float* __restrict__ out) {
  __shared__ float wsum[8];
  const int t = threadIdx.x;
  float sum = 0.f;
  const float cM = 0.87758256189037271f;  // cos(0.5)
  const float sM = 0.47942553860420301f;  // sin(0.5)
  for (int i = t; i < BN; i += 512) {
    const float tg_raw = tgt[i];
    const float tg = fminf(fmaxf(tg_raw, -1.f + 1e-7f), 1.f - 1e-7f);
    const float num = 64.f * (tg * cM - sqrtf(fmaxf(1.f - tg * tg, 0.f)) * sM);
    const float den = expf(num) + rowsum[i] - expf(64.f * tg_raw);
    sum += num - logf(den);
  }
#pragma unroll
  for (int off = 1; off < 64; off <<= 1) sum += __shfl_xor(sum, off, 64);
  if ((t & 63) == 0) wsum[t >> 6] = sum;
  __syncthreads();
  if (t == 0) {
    float tot = 0.f;
#pragma unroll
    for (int k = 0; k < 8; ++k) tot += wsum[k];
    out[0] = -tot * (1.0f / (float)BN);
  }
}

extern "C" void kernel_launch(void* const* d_in, const int* in_sizes, int n_in,
                              void* d_out, int out_size, void* d_ws, size_t ws_size,
                              hipStream_t stream) {
  const float* features = (const float*)d_in[0];
  const int*   y_true   = (const int*)d_in[1];
  const float* weight   = (const float*)d_in[2];
  float* out = (float*)d_out;

  char* ws = (char*)d_ws;
  char* wb8    = ws;                          // 16 MB
  char* fb8    = ws + 16777216;               //  1 MB
  float* tgt    = (float*)(ws + 17825792);    //  8 KB
  float* rowsum = (float*)(ws + 17833984);    //  8 KB

  prep_kernel<<<8192 + 512, 256, 0, stream>>>(features, y_true, weight,
                                              (int*)fb8, (int*)wb8, tgt, rowsum);
  gemm_exp_kernel<<<2048, 512, 0, stream>>>(fb8, wb8, rowsum);
  loss_kernel<<<1, 512, 0, stream>>>(tgt, rowsum, out);
}

// Round 2
// 295.551 us; speedup vs baseline: 1.6625x; 1.6625x over previous
//
#include <hip/hip_runtime.h>
#include <hip/hip_bf16.h>
#include <math.h>

// ArcFace loss, MI355X. B=2048, D=512, C=32768.
// R11: MX-scaled fp8 GEMM via mfma_scale_f32_32x32x64_f8f6f4 (unit scales,
// E8M0 0x7F = 2^0; 2x the non-scaled fp8 rate). K=64 per MFMA = exactly one
// LDS slab, so no cross-slab register carry (R10's aL/bL + a4/b4 live set
// of ~164 VGPRs blew the 128 cap from launch_bounds(512,4) and collapsed
// into scratch: FETCH 864MB/WRITE 787MB). Per-wave 64x64 = 2x2 fragments
// of 32x32: acc 64 + operands 32 + addressing ~20 = ~116 VGPRs, fits 128.
// A/B lane map: row/col = lane&31, k-half = (lane>>5)*32B; each lane reads
// global units {2q, 2q+1} of its row through the unchanged XOR-rotation
// store (bijective k-permutation identical for A and B, so the contraction
// is exact — validated bit-exact in R10). C/D 32x32 layout:
// col=lane&31, row=(reg&3)+8*(reg>>2)+4*(lane>>5). Staging, prefetch,
// barriers, prep, loss unchanged from R9.

#define BN 2048
#define DK 512
#define CN 32768

typedef __attribute__((ext_vector_type(4))) float floatx4;
typedef __attribute__((ext_vector_type(16))) float floatx16;
typedef __attribute__((ext_vector_type(2))) long longx2;
typedef __attribute__((ext_vector_type(4))) long longx4;
typedef __attribute__((ext_vector_type(8))) int intx8;

__device__ inline float dot4(floatx4 a, floatx4 b) {
  return a.x * b.x + a.y * b.y + a.z * b.z + a.w * b.w;
}

__device__ inline int pack_fp8x4(floatx4 v) {
  int r = __builtin_amdgcn_cvt_pk_fp8_f32(v.x, v.y, 0, false);
  r = __builtin_amdgcn_cvt_pk_fp8_f32(v.z, v.w, r, true);
  return r;
}

// dword j (0..15) of a 64B slab -> MFMA-ready position:
// q=(j>>1)&3 (8B piece), p=j>>3 (k-step), dest = q*4 + p*2 + (j&1)
__device__ inline int permute16(int j) {
  return ((j >> 1) & 3) * 4 + (j >> 3) * 2 + (j & 1);
}

__device__ inline void async_ld16(const void* g, void* l) {
  __builtin_amdgcn_global_load_lds(
      (const __attribute__((address_space(1))) void*)g,
      (__attribute__((address_space(3))) void*)l, 16, 0, 0);
}

// ---- kernel 1: fused prep -> fp8 rows (512 B each), MFMA-ready byte order.
__global__ void prep_kernel(const float* __restrict__ feat,
                            const int* __restrict__ y,
                            const float* __restrict__ w,
                            int* __restrict__ fb8,     // [BN][128] dwords
                            int* __restrict__ wb8,     // [CN][128] dwords
                            float* __restrict__ tgt,
                            float* __restrict__ rowsum) {
  const int wave = threadIdx.x >> 6;
  const int l = threadIdx.x & 63;
  const int d0 = ((l >> 4) * 16)       + permute16(l & 15);
  const int d1 = ((4 + (l >> 4)) * 16) + permute16(l & 15);
  if (blockIdx.x < 8192) {
    const int row = blockIdx.x * 4 + wave;
    const floatx4* src = (const floatx4*)(w + (size_t)row * DK);
    floatx4 v0 = src[l];
    floatx4 v1 = src[64 + l];
    float s = dot4(v0, v0) + dot4(v1, v1);
#pragma unroll
    for (int off = 1; off < 64; off <<= 1) s += __shfl_xor(s, off, 64);
    const float scale = 1.0f / fmaxf(sqrtf(s), 1e-12f);
    v0 *= scale; v1 *= scale;
    int* db = wb8 + (size_t)row * 128;
    db[d0] = pack_fp8x4(v0);
    db[d1] = pack_fp8x4(v1);
  } else {
    const int i = (blockIdx.x - 8192) * 4 + wave;
    const floatx4* src = (const floatx4*)(feat + (size_t)i * DK);
    floatx4 v0 = src[l];
    floatx4 v1 = src[64 + l];
    const int cls = y[i];
    const floatx4* wr = (const floatx4*)(w + (size_t)cls * DK);
    floatx4 w0 = wr[l], w1 = wr[64 + l];
    float s  = dot4(v0, v0) + dot4(v1, v1);
    float d  = dot4(v0, w0) + dot4(v1, w1);
    float wn = dot4(w0, w0) + dot4(w1, w1);
#pragma unroll
    for (int off = 1; off < 64; off <<= 1) {
      s  += __shfl_xor(s, off, 64);
      d  += __shfl_xor(d, off, 64);
      wn += __shfl_xor(wn, off, 64);
    }
    const float fscale = 1.0f / fmaxf(sqrtf(s), 1e-12f);
    v0 *= fscale; v1 *= fscale;
    int* db = fb8 + (size_t)i * 128;
    db[d0] = pack_fp8x4(v0);
    db[d1] = pack_fp8x4(v1);
    if (l == 0) {
      tgt[i] = d * fscale / fmaxf(sqrtf(wn), 1e-12f);
      rowsum[i] = 0.0f;
    }
  }
}

// ---- kernel 2: 128(M)x256(N) MX-fp8 MFMA GEMM (32x32x64, unit scales),
// ping-pong LDS, one barrier per K-64 slab, fused exp row-sum.
__launch_bounds__(512, 4)
__global__ void gemm_exp_kernel(const char* __restrict__ fb8,   // [BN][512] B
                                const char* __restrict__ wb8,   // [CN][512] B
                                float* __restrict__ rowsum) {
  __shared__ char As[2][128 * 64];   // 2 x  8 KB
  __shared__ char Bs[2][256 * 64];   // 2 x 16 KB
  __shared__ float lsum[128];

  const int tid  = threadIdx.x;
  const int wave = tid >> 6;
  const int lane = tid & 63;

  // XCD swizzle: n -> (x: M-tile 0..15, y: N-tile 0..127); XCD(n%8) owns y%8.
  const int n = blockIdx.x;
  const int tileM = ((n >> 3) & 15) * 128;
  const int tileN = (((n >> 7) << 3) | (n & 7)) * 256;

  const int wm = (wave >> 2) * 64;  // wave M offset (0 or 64)
  const int wn = (wave & 3) * 64;   // wave N offset (0..192)

  if (tid < 128) lsum[tid] = 0.0f;  // covered by first K-loop barrier

  floatx16 acc[2][2];
#pragma unroll
  for (int ti = 0; ti < 2; ++ti)
#pragma unroll
    for (int tj = 0; tj < 2; ++tj)
#pragma unroll
      for (int r = 0; r < 16; ++r)
        acc[ti][tj][r] = 0.0f;

  // staging (unchanged): unit c -> row c>>2, stored pos c&3;
  // fetch global unit (c&3)^((row>>1)&3).
  const int mA = tid >> 2;
  const int uA = (tid & 3) ^ ((mA >> 1) & 3);
  const int mB1 = (512 + tid) >> 2;
  const int uB1 = (tid & 3) ^ ((mB1 >> 1) & 3);
  const char* gA  = fb8 + (size_t)(tileM + mA)  * DK + uA  * 16;
  const char* gB0 = wb8 + (size_t)(tileN + mA)  * DK + uA  * 16;   // rows 0..127
  const char* gB1 = wb8 + (size_t)(tileN + mB1) * DK + uB1 * 16;   // rows 128..255
  const int ldsA  = wave * 1024;         // wave-uniform LDS offsets
  const int ldsB0 = wave * 1024;
  const int ldsB1 = 8192 + wave * 1024;

  // hoisted fragment LDS byte-offsets (loop-invariant).
  // Lane needs row = base + (lane&31), global units {2q, 2q+1}, q = lane>>5;
  // stored position of global unit u in row r is u ^ ((r>>1)&3).
  const int r31 = lane & 31;
  const int q2  = (lane >> 5) * 2;
  int offA0[2], offA1[2], offB0[2], offB1[2];
#pragma unroll
  for (int ti = 0; ti < 2; ++ti) {
    const int row = wm + ti * 32 + r31;
    const int rot = (row >> 1) & 3;
    offA0[ti] = row * 64 + ((q2    ) ^ rot) * 16;
    offA1[ti] = row * 64 + ((q2 + 1) ^ rot) * 16;
  }
#pragma unroll
  for (int tj = 0; tj < 2; ++tj) {
    const int row = wn + tj * 32 + r31;
    const int rot = (row >> 1) & 3;
    offB0[tj] = row * 64 + ((q2    ) ^ rot) * 16;
    offB1[tj] = row * 64 + ((q2 + 1) ^ rot) * 16;
  }

  // prologue: stage slab 0 into buffer 0
  async_ld16(gA,  &As[0][ldsA]);
  async_ld16(gB0, &Bs[0][ldsB0]);
  async_ld16(gB1, &Bs[0][ldsB1]);
  gA += 64; gB0 += 64; gB1 += 64;

#pragma unroll
  for (int kk = 0; kk < DK / 64; ++kk) {
    const int cur = kk & 1;
    // Barrier: (a) drains this wave's vmcnt -> buf[cur] resident (its loads
    // were issued one full iteration ago); (b) all waves done with buf[cur^1].
    __syncthreads();
    if (kk < DK / 64 - 1) {
      const int nxt = cur ^ 1;
      async_ld16(gA,  &As[nxt][ldsA]);
      async_ld16(gB0, &Bs[nxt][ldsB0]);
      async_ld16(gB1, &Bs[nxt][ldsB1]);
      gA += 64; gB0 += 64; gB1 += 64;
    }

    const char* Ab = As[cur];
    const char* Bb = Bs[cur];
    intx8 a[2], b[2];
#pragma unroll
    for (int ti = 0; ti < 2; ++ti) {
      longx2 lo = *(const longx2*)(Ab + offA0[ti]);
      longx2 hi = *(const longx2*)(Ab + offA1[ti]);
      longx4 t = (longx4){lo.x, lo.y, hi.x, hi.y};
      a[ti] = (intx8)t;
    }
#pragma unroll
    for (int tj = 0; tj < 2; ++tj) {
      longx2 lo = *(const longx2*)(Bb + offB0[tj]);
      longx2 hi = *(const longx2*)(Bb + offB1[tj]);
      longx4 t = (longx4){lo.x, lo.y, hi.x, hi.y};
      b[tj] = (intx8)t;
    }
    // 4 MX-scaled MFMAs, K=64, unit scales (0x7F = 2^0): per-product
    // identical to the non-scaled fp8 path; A and B share the same
    // k-permutation so the contraction is exact.
#pragma unroll
    for (int ti = 0; ti < 2; ++ti)
#pragma unroll
      for (int tj = 0; tj < 2; ++tj)
        acc[ti][tj] = __builtin_amdgcn_mfma_scale_f32_32x32x64_f8f6f4(
            a[ti], b[tj], acc[ti][tj],
            0, 0, 0, 0x7f7f7f7f, 0, 0x7f7f7f7f);
  }

  // epilogue: rowsum[m] += sum_n exp(64 * wf[m][n])
  // C/D 32x32 layout: col = lane&31, row = (reg&3) + 8*(reg>>2) + 4*(lane>>5)
  const int qrow = (lane >> 5) * 4;
#pragma unroll
  for (int ti = 0; ti < 2; ++ti) {
#pragma unroll
    for (int r = 0; r < 16; ++r) {
      float v = __expf(64.0f * acc[ti][0][r]) + __expf(64.0f * acc[ti][1][r]);
      v += __shfl_xor(v, 1, 64);
      v += __shfl_xor(v, 2, 64);
      v += __shfl_xor(v, 4, 64);
      v += __shfl_xor(v, 8, 64);
      v += __shfl_xor(v, 16, 64);
      if ((lane & 31) == 0)
        atomicAdd(&lsum[wm + ti * 32 + qrow + (r & 3) + 8 * (r >> 2)], v);
    }
  }
  __syncthreads();
  if (tid < 128)
    atomicAdd(&rowsum[tileM + tid], lsum[tid]);
}

// ---- kernel 3: final loss
__global__ void loss_kernel(const float* __restrict__ tgt,
                            const float* __restrict__ rowsum,
                            float* __restrict__ out) {
  __shared__ float wsum[8];
  const int t = threadIdx.x;
  float sum = 0.f;
  const float cM = 0.87758256189037271f;  // cos(0.5)
  const float sM = 0.47942553860420301f;  // sin(0.5)
  for (int i = t; i < BN; i += 512) {
    const float tg_raw = tgt[i];
    const float tg = fminf(fmaxf(tg_raw, -1.f + 1e-7f), 1.f - 1e-7f);
    const float num = 64.f * (tg * cM - sqrtf(fmaxf(1.f - tg * tg, 0.f)) * sM);
    const float den = expf(num) + rowsum[i] - expf(64.f * tg_raw);
    sum += num - logf(den);
  }
#pragma unroll
  for (int off = 1; off < 64; off <<= 1) sum += __shfl_xor(sum, off, 64);
  if ((t & 63) == 0) wsum[t >> 6] = sum;
  __syncthreads();
  if (t == 0) {
    float tot = 0.f;
#pragma unroll
    for (int k = 0; k < 8; ++k) tot += wsum[k];
    out[0] = -tot * (1.0f / (float)BN);
  }
}

extern "C" void kernel_launch(void* const* d_in, const int* in_sizes, int n_in,
                              void* d_out, int out_size, void* d_ws, size_t ws_size,
                              hipStream_t stream) {
  const float* features = (const float*)d_in[0];
  const int*   y_true   = (const int*)d_in[1];
  const float* weight   = (const float*)d_in[2];
  float* out = (float*)d_out;

  char* ws = (char*)d_ws;
  char* wb8    = ws;                          // 16 MB
  char* fb8    = ws + 16777216;               //  1 MB
  float* tgt    = (float*)(ws + 17825792);    //  8 KB
  float* rowsum = (float*)(ws + 17833984);    //  8 KB

  prep_kernel<<<8192 + 512, 256, 0, stream>>>(features, y_true, weight,
                                              (int*)fb8, (int*)wb8, tgt, rowsum);
  gemm_exp_kernel<<<2048, 512, 0, stream>>>(fb8, wb8, rowsum);
  loss_kernel<<<1, 512, 0, stream>>>(tgt, rowsum, out);
}

// Round 3
// 242.055 us; speedup vs baseline: 2.0299x; 1.2210x over previous
//
#include <hip/hip_runtime.h>
#include <hip/hip_bf16.h>
#include <math.h>

// ArcFace loss, MI355X. B=2048, D=512, C=32768.
// R12: MX-scaled fp8 GEMM (mfma_scale_f32_32x32x64_f8f6f4, unit scales
// 0x7F = 2^0, 2x non-scaled fp8 rate; layouts bit-exact-verified in R11).
// R10/R11 failed on REGISTERS, not math: launch_bounds(512,4) caps the
// unified VGPR+AGPR file at 128/wave; acc(64, AGPR half) left 64 arch
// VGPRs for four 8-aligned intx8 operand tuples + addressing -> ~500B/
// thread scratch spill (WRITE 525MB). Fix: 256-thread blocks, tile
// 128x128, per-wave 64x64 unchanged, launch_bounds(256,3) -> 170-reg cap
// (live ~134), 3 blocks/CU. Epilogue drops the shfl_xor(..,16) level
// (suspect for R11's 4.2M bank conflicts): 4-level tree + 2-way lsum
// atomics. Staging/XOR-rotation/ping-pong/prep/loss unchanged.

#define BN 2048
#define DK 512
#define CN 32768

typedef __attribute__((ext_vector_type(4))) float floatx4;
typedef __attribute__((ext_vector_type(16))) float floatx16;
typedef __attribute__((ext_vector_type(2))) long longx2;
typedef __attribute__((ext_vector_type(4))) long longx4;
typedef __attribute__((ext_vector_type(8))) int intx8;

__device__ inline float dot4(floatx4 a, floatx4 b) {
  return a.x * b.x + a.y * b.y + a.z * b.z + a.w * b.w;
}

__device__ inline int pack_fp8x4(floatx4 v) {
  int r = __builtin_amdgcn_cvt_pk_fp8_f32(v.x, v.y, 0, false);
  r = __builtin_amdgcn_cvt_pk_fp8_f32(v.z, v.w, r, true);
  return r;
}

// dword j (0..15) of a 64B slab -> MFMA-ready position:
// q=(j>>1)&3 (8B piece), p=j>>3 (k-step), dest = q*4 + p*2 + (j&1)
__device__ inline int permute16(int j) {
  return ((j >> 1) & 3) * 4 + (j >> 3) * 2 + (j & 1);
}

__device__ inline void async_ld16(const void* g, void* l) {
  __builtin_amdgcn_global_load_lds(
      (const __attribute__((address_space(1))) void*)g,
      (__attribute__((address_space(3))) void*)l, 16, 0, 0);
}

// ---- kernel 1: fused prep -> fp8 rows (512 B each), MFMA-ready byte order.
__global__ void prep_kernel(const float* __restrict__ feat,
                            const int* __restrict__ y,
                            const float* __restrict__ w,
                            int* __restrict__ fb8,     // [BN][128] dwords
                            int* __restrict__ wb8,     // [CN][128] dwords
                            float* __restrict__ tgt,
                            float* __restrict__ rowsum) {
  const int wave = threadIdx.x >> 6;
  const int l = threadIdx.x & 63;
  const int d0 = ((l >> 4) * 16)       + permute16(l & 15);
  const int d1 = ((4 + (l >> 4)) * 16) + permute16(l & 15);
  if (blockIdx.x < 8192) {
    const int row = blockIdx.x * 4 + wave;
    const floatx4* src = (const floatx4*)(w + (size_t)row * DK);
    floatx4 v0 = src[l];
    floatx4 v1 = src[64 + l];
    float s = dot4(v0, v0) + dot4(v1, v1);
#pragma unroll
    for (int off = 1; off < 64; off <<= 1) s += __shfl_xor(s, off, 64);
    const float scale = 1.0f / fmaxf(sqrtf(s), 1e-12f);
    v0 *= scale; v1 *= scale;
    int* db = wb8 + (size_t)row * 128;
    db[d0] = pack_fp8x4(v0);
    db[d1] = pack_fp8x4(v1);
  } else {
    const int i = (blockIdx.x - 8192) * 4 + wave;
    const floatx4* src = (const floatx4*)(feat + (size_t)i * DK);
    floatx4 v0 = src[l];
    floatx4 v1 = src[64 + l];
    const int cls = y[i];
    const floatx4* wr = (const floatx4*)(w + (size_t)cls * DK);
    floatx4 w0 = wr[l], w1 = wr[64 + l];
    float s  = dot4(v0, v0) + dot4(v1, v1);
    float d  = dot4(v0, w0) + dot4(v1, w1);
    float wn = dot4(w0, w0) + dot4(w1, w1);
#pragma unroll
    for (int off = 1; off < 64; off <<= 1) {
      s  += __shfl_xor(s, off, 64);
      d  += __shfl_xor(d, off, 64);
      wn += __shfl_xor(wn, off, 64);
    }
    const float fscale = 1.0f / fmaxf(sqrtf(s), 1e-12f);
    v0 *= fscale; v1 *= fscale;
    int* db = fb8 + (size_t)i * 128;
    db[d0] = pack_fp8x4(v0);
    db[d1] = pack_fp8x4(v1);
    if (l == 0) {
      tgt[i] = d * fscale / fmaxf(sqrtf(wn), 1e-12f);
      rowsum[i] = 0.0f;
    }
  }
}

// ---- kernel 2: 128(M)x128(N) MX-fp8 MFMA GEMM (32x32x64, unit scales),
// 256 threads (4 waves, 2Mx2N), ping-pong LDS, one barrier per K-64 slab,
// fused exp row-sum.
__launch_bounds__(256, 3)
__global__ void gemm_exp_kernel(const char* __restrict__ fb8,   // [BN][512] B
                                const char* __restrict__ wb8,   // [CN][512] B
                                float* __restrict__ rowsum) {
  __shared__ char As[2][128 * 64];   // 2 x 8 KB
  __shared__ char Bs[2][128 * 64];   // 2 x 8 KB
  __shared__ float lsum[128];

  const int tid  = threadIdx.x;
  const int wave = tid >> 6;
  const int lane = tid & 63;

  // XCD swizzle: n bits {b11..b7}=Ngroup, {b6..b3}=M-tile, {b2..b0}=xcd.
  // N-tile = Ngroup*8 + xcd, so XCD x owns N-tiles == x (mod 8): bijective.
  const int n = blockIdx.x;
  const int tileM = ((n >> 3) & 15) * 128;
  const int tileN = (((n >> 7) << 3) | (n & 7)) * 128;

  const int wm = (wave >> 1) * 64;  // wave M offset (0 or 64)
  const int wn = (wave & 1) * 64;   // wave N offset (0 or 64)

  if (tid < 128) lsum[tid] = 0.0f;  // covered by first K-loop barrier

  floatx16 acc[2][2];
#pragma unroll
  for (int ti = 0; ti < 2; ++ti)
#pragma unroll
    for (int tj = 0; tj < 2; ++tj)
#pragma unroll
      for (int r = 0; r < 16; ++r)
        acc[ti][tj][r] = 0.0f;

  // staging: chunk c (of 512 per matrix per slab) -> row c>>2, stored pos
  // c&3; fetched global unit (c&3)^((row>>1)&3). Thread t handles chunks
  // {t, t+256} of A and of B (4 async_ld16 per slab). LDS dest is linear
  // (chunk*16), i.e. wave-uniform base + lane*16 per call.
  const int rowL = tid >> 2;                         // rows 0..63
  const int uL   = (tid & 3) ^ ((rowL >> 1) & 3);    // same for row+64
  const char* gA1 = fb8 + (size_t)(tileM + rowL)      * DK + uL * 16;
  const char* gA2 = fb8 + (size_t)(tileM + rowL + 64) * DK + uL * 16;
  const char* gB1 = wb8 + (size_t)(tileN + rowL)      * DK + uL * 16;
  const char* gB2 = wb8 + (size_t)(tileN + rowL + 64) * DK + uL * 16;
  const int ldsO1 = wave * 1024;          // chunks t      -> bytes [0,4096)
  const int ldsO2 = 4096 + wave * 1024;   // chunks t+256  -> bytes [4096,8192)

  // hoisted fragment LDS byte-offsets (loop-invariant).
  // Lane: row = base + (lane&31), global units {2q, 2q+1}, q = lane>>5;
  // stored position of unit u in row r is u ^ ((r>>1)&3).
  const int r31 = lane & 31;
  const int q2  = (lane >> 5) * 2;
  int offA0[2], offA1[2], offB0[2], offB1[2];
#pragma unroll
  for (int ti = 0; ti < 2; ++ti) {
    const int row = wm + ti * 32 + r31;
    const int rot = (row >> 1) & 3;
    offA0[ti] = row * 64 + ((q2    ) ^ rot) * 16;
    offA1[ti] = row * 64 + ((q2 + 1) ^ rot) * 16;
  }
#pragma unroll
  for (int tj = 0; tj < 2; ++tj) {
    const int row = wn + tj * 32 + r31;
    const int rot = (row >> 1) & 3;
    offB0[tj] = row * 64 + ((q2    ) ^ rot) * 16;
    offB1[tj] = row * 64 + ((q2 + 1) ^ rot) * 16;
  }

  // prologue: stage slab 0 into buffer 0
  async_ld16(gA1, &As[0][ldsO1]);
  async_ld16(gA2, &As[0][ldsO2]);
  async_ld16(gB1, &Bs[0][ldsO1]);
  async_ld16(gB2, &Bs[0][ldsO2]);
  gA1 += 64; gA2 += 64; gB1 += 64; gB2 += 64;

#pragma unroll
  for (int kk = 0; kk < DK / 64; ++kk) {
    const int cur = kk & 1;
    // Barrier: (a) drains this wave's vmcnt -> buf[cur] resident (its loads
    // were issued one full iteration ago); (b) all waves done with buf[cur^1].
    __syncthreads();
    if (kk < DK / 64 - 1) {
      const int nxt = cur ^ 1;
      async_ld16(gA1, &As[nxt][ldsO1]);
      async_ld16(gA2, &As[nxt][ldsO2]);
      async_ld16(gB1, &Bs[nxt][ldsO1]);
      async_ld16(gB2, &Bs[nxt][ldsO2]);
      gA1 += 64; gA2 += 64; gB1 += 64; gB2 += 64;
    }

    const char* Ab = As[cur];
    const char* Bb = Bs[cur];
    intx8 a[2], b[2];
#pragma unroll
    for (int ti = 0; ti < 2; ++ti) {
      longx2 lo = *(const longx2*)(Ab + offA0[ti]);
      longx2 hi = *(const longx2*)(Ab + offA1[ti]);
      longx4 t = (longx4){lo.x, lo.y, hi.x, hi.y};
      a[ti] = (intx8)t;
    }
#pragma unroll
    for (int tj = 0; tj < 2; ++tj) {
      longx2 lo = *(const longx2*)(Bb + offB0[tj]);
      longx2 hi = *(const longx2*)(Bb + offB1[tj]);
      longx4 t = (longx4){lo.x, lo.y, hi.x, hi.y};
      b[tj] = (intx8)t;
    }
    // 4 MX-scaled MFMAs, K=64, unit scales (0x7F = 2^0): per-product
    // identical to the non-scaled fp8 path; A and B share the same
    // k-permutation so the contraction is exact (bit-exact in R11).
#pragma unroll
    for (int ti = 0; ti < 2; ++ti)
#pragma unroll
      for (int tj = 0; tj < 2; ++tj)
        acc[ti][tj] = __builtin_amdgcn_mfma_scale_f32_32x32x64_f8f6f4(
            a[ti], b[tj], acc[ti][tj],
            0, 0, 0, 0x7f7f7f7f, 0, 0x7f7f7f7f);
  }

  // epilogue: rowsum[m] += sum_n exp(64 * wf[m][n])
  // C/D 32x32 layout: col = lane&31, row = (reg&3) + 8*(reg>>2) + 4*(lane>>5).
  // 4-level tree (no xor-16): lanes 0/16 (and 32/48) hold 16-col halves of
  // the same row -> both atomicAdd (2-way LDS atomic).
  const int qrow = (lane >> 5) * 4;
#pragma unroll
  for (int ti = 0; ti < 2; ++ti) {
#pragma unroll
    for (int r = 0; r < 16; ++r) {
      float v = __expf(64.0f * acc[ti][0][r]) + __expf(64.0f * acc[ti][1][r]);
      v += __shfl_xor(v, 1, 64);
      v += __shfl_xor(v, 2, 64);
      v += __shfl_xor(v, 4, 64);
      v += __shfl_xor(v, 8, 64);
      if ((lane & 15) == 0)
        atomicAdd(&lsum[wm + ti * 32 + qrow + (r & 3) + 8 * (r >> 2)], v);
    }
  }
  __syncthreads();
  if (tid < 128)
    atomicAdd(&rowsum[tileM + tid], lsum[tid]);
}

// ---- kernel 3: final loss
__global__ void loss_kernel(const float* __restrict__ tgt,
                            const float* __restrict__ rowsum,
                            float* __restrict__ out) {
  __shared__ float wsum[8];
  const int t = threadIdx.x;
  float sum = 0.f;
  const float cM = 0.87758256189037271f;  // cos(0.5)
  const float sM = 0.47942553860420301f;  // sin(0.5)
  for (int i = t; i < BN; i += 512) {
    const float tg_raw = tgt[i];
    const float tg = fminf(fmaxf(tg_raw, -1.f + 1e-7f), 1.f - 1e-7f);
    const float num = 64.f * (tg * cM - sqrtf(fmaxf(1.f - tg * tg, 0.f)) * sM);
    const float den = expf(num) + rowsum[i] - expf(64.f * tg_raw);
    sum += num - logf(den);
  }
#pragma unroll
  for (int off = 1; off < 64; off <<= 1) sum += __shfl_xor(sum, off, 64);
  if ((t & 63) == 0) wsum[t >> 6] = sum;
  __syncthreads();
  if (t == 0) {
    float tot = 0.f;
#pragma unroll
    for (int k = 0; k < 8; ++k) tot += wsum[k];
    out[0] = -tot * (1.0f / (float)BN);
  }
}

extern "C" void kernel_launch(void* const* d_in, const int* in_sizes, int n_in,
                              void* d_out, int out_size, void* d_ws, size_t ws_size,
                              hipStream_t stream) {
  const float* features = (const float*)d_in[0];
  const int*   y_true   = (const int*)d_in[1];
  const float* weight   = (const float*)d_in[2];
  float* out = (float*)d_out;

  char* ws = (char*)d_ws;
  char* wb8    = ws;                          // 16 MB
  char* fb8    = ws + 16777216;               //  1 MB
  float* tgt    = (float*)(ws + 17825792);    //  8 KB
  float* rowsum = (float*)(ws + 17833984);    //  8 KB

  prep_kernel<<<8192 + 512, 256, 0, stream>>>(features, y_true, weight,
                                              (int*)fb8, (int*)wb8, tgt, rowsum);
  gemm_exp_kernel<<<4096, 256, 0, stream>>>(fb8, wb8, rowsum);
  loss_kernel<<<1, 512, 0, stream>>>(tgt, rowsum, out);
}

// Round 5
// 192.308 us; speedup vs baseline: 2.5550x; 1.2587x over previous
//
#include <hip/hip_runtime.h>
#include <hip/hip_bf16.h>
#include <math.h>

// ArcFace loss, MI355X. B=2048, D=512, C=32768.
// R13 (resubmit; previous round was an infra failure — container acquisition
// died twice, kernel never ran). MX-scaled fp8 GEMM
// (mfma_scale_f32_32x32x64_f8f6f4, unit scales 0x7F = 2^0, 2x non-scaled
// fp8 rate; layouts bit-exact since R11).
// R11/R12 showed the allocator splits the unified reg budget ~evenly into
// VGPR/AGPR halves (cap 128 -> 64 arch VGPR; cap 170 -> 84): the arch half
// must hold four 8-aligned intx8 operand tuples + addressing and kept
// spilling ~345 B/thread (WRITE 362MB, FETCH 233MB of scratch). R13 keeps
// R12's geometry (256 thr, 128x128 tile, 64x64/wave) and changes ONE
// variable: launch_bounds(256,2) -> 256 regs/wave (128 VGPR + 128 AGPR),
// 2 blocks/CU. acc(64) fits AGPR half, operands+addressing (~90) fit VGPR
// half -> no spill. Staging/XOR-rotation/ping-pong/prep/loss unchanged.

#define BN 2048
#define DK 512
#define CN 32768

typedef __attribute__((ext_vector_type(4))) float floatx4;
typedef __attribute__((ext_vector_type(16))) float floatx16;
typedef __attribute__((ext_vector_type(2))) long longx2;
typedef __attribute__((ext_vector_type(4))) long longx4;
typedef __attribute__((ext_vector_type(8))) int intx8;

__device__ inline float dot4(floatx4 a, floatx4 b) {
  return a.x * b.x + a.y * b.y + a.z * b.z + a.w * b.w;
}

__device__ inline int pack_fp8x4(floatx4 v) {
  int r = __builtin_amdgcn_cvt_pk_fp8_f32(v.x, v.y, 0, false);
  r = __builtin_amdgcn_cvt_pk_fp8_f32(v.z, v.w, r, true);
  return r;
}

// dword j (0..15) of a 64B slab -> MFMA-ready position:
// q=(j>>1)&3 (8B piece), p=j>>3 (k-step), dest = q*4 + p*2 + (j&1)
__device__ inline int permute16(int j) {
  return ((j >> 1) & 3) * 4 + (j >> 3) * 2 + (j & 1);
}

__device__ inline void async_ld16(const void* g, void* l) {
  __builtin_amdgcn_global_load_lds(
      (const __attribute__((address_space(1))) void*)g,
      (__attribute__((address_space(3))) void*)l, 16, 0, 0);
}

// ---- kernel 1: fused prep -> fp8 rows (512 B each), MFMA-ready byte order.
__global__ void prep_kernel(const float* __restrict__ feat,
                            const int* __restrict__ y,
                            const float* __restrict__ w,
                            int* __restrict__ fb8,     // [BN][128] dwords
                            int* __restrict__ wb8,     // [CN][128] dwords
                            float* __restrict__ tgt,
                            float* __restrict__ rowsum) {
  const int wave = threadIdx.x >> 6;
  const int l = threadIdx.x & 63;
  const int d0 = ((l >> 4) * 16)       + permute16(l & 15);
  const int d1 = ((4 + (l >> 4)) * 16) + permute16(l & 15);
  if (blockIdx.x < 8192) {
    const int row = blockIdx.x * 4 + wave;
    const floatx4* src = (const floatx4*)(w + (size_t)row * DK);
    floatx4 v0 = src[l];
    floatx4 v1 = src[64 + l];
    float s = dot4(v0, v0) + dot4(v1, v1);
#pragma unroll
    for (int off = 1; off < 64; off <<= 1) s += __shfl_xor(s, off, 64);
    const float scale = 1.0f / fmaxf(sqrtf(s), 1e-12f);
    v0 *= scale; v1 *= scale;
    int* db = wb8 + (size_t)row * 128;
    db[d0] = pack_fp8x4(v0);
    db[d1] = pack_fp8x4(v1);
  } else {
    const int i = (blockIdx.x - 8192) * 4 + wave;
    const floatx4* src = (const floatx4*)(feat + (size_t)i * DK);
    floatx4 v0 = src[l];
    floatx4 v1 = src[64 + l];
    const int cls = y[i];
    const floatx4* wr = (const floatx4*)(w + (size_t)cls * DK);
    floatx4 w0 = wr[l], w1 = wr[64 + l];
    float s  = dot4(v0, v0) + dot4(v1, v1);
    float d  = dot4(v0, w0) + dot4(v1, w1);
    float wn = dot4(w0, w0) + dot4(w1, w1);
#pragma unroll
    for (int off = 1; off < 64; off <<= 1) {
      s  += __shfl_xor(s, off, 64);
      d  += __shfl_xor(d, off, 64);
      wn += __shfl_xor(wn, off, 64);
    }
    const float fscale = 1.0f / fmaxf(sqrtf(s), 1e-12f);
    v0 *= fscale; v1 *= fscale;
    int* db = fb8 + (size_t)i * 128;
    db[d0] = pack_fp8x4(v0);
    db[d1] = pack_fp8x4(v1);
    if (l == 0) {
      tgt[i] = d * fscale / fmaxf(sqrtf(wn), 1e-12f);
      rowsum[i] = 0.0f;
    }
  }
}

// ---- kernel 2: 128(M)x128(N) MX-fp8 MFMA GEMM (32x32x64, unit scales),
// 256 threads (4 waves, 2Mx2N), ping-pong LDS, one barrier per K-64 slab,
// fused exp row-sum.
__launch_bounds__(256, 2)
__global__ void gemm_exp_kernel(const char* __restrict__ fb8,   // [BN][512] B
                                const char* __restrict__ wb8,   // [CN][512] B
                                float* __restrict__ rowsum) {
  __shared__ char As[2][128 * 64];   // 2 x 8 KB
  __shared__ char Bs[2][128 * 64];   // 2 x 8 KB
  __shared__ float lsum[128];

  const int tid  = threadIdx.x;
  const int wave = tid >> 6;
  const int lane = tid & 63;

  // XCD swizzle: n bits {b11..b7}=Ngroup, {b6..b3}=M-tile, {b2..b0}=xcd.
  // N-tile = Ngroup*8 + xcd, so XCD x owns N-tiles == x (mod 8): bijective.
  const int n = blockIdx.x;
  const int tileM = ((n >> 3) & 15) * 128;
  const int tileN = (((n >> 7) << 3) | (n & 7)) * 128;

  const int wm = (wave >> 1) * 64;  // wave M offset (0 or 64)
  const int wn = (wave & 1) * 64;   // wave N offset (0 or 64)

  if (tid < 128) lsum[tid] = 0.0f;  // covered by first K-loop barrier

  floatx16 acc[2][2];
#pragma unroll
  for (int ti = 0; ti < 2; ++ti)
#pragma unroll
    for (int tj = 0; tj < 2; ++tj)
#pragma unroll
      for (int r = 0; r < 16; ++r)
        acc[ti][tj][r] = 0.0f;

  // staging: chunk c (of 512 per matrix per slab) -> row c>>2, stored pos
  // c&3; fetched global unit (c&3)^((row>>1)&3). Thread t handles chunks
  // {t, t+256} of A and of B (4 async_ld16 per slab). LDS dest is linear
  // (chunk*16), i.e. wave-uniform base + lane*16 per call.
  const int rowL = tid >> 2;                         // rows 0..63
  const int uL   = (tid & 3) ^ ((rowL >> 1) & 3);    // same for row+64
  const char* gA1 = fb8 + (size_t)(tileM + rowL)      * DK + uL * 16;
  const char* gA2 = fb8 + (size_t)(tileM + rowL + 64) * DK + uL * 16;
  const char* gB1 = wb8 + (size_t)(tileN + rowL)      * DK + uL * 16;
  const char* gB2 = wb8 + (size_t)(tileN + rowL + 64) * DK + uL * 16;
  const int ldsO1 = wave * 1024;          // chunks t      -> bytes [0,4096)
  const int ldsO2 = 4096 + wave * 1024;   // chunks t+256  -> bytes [4096,8192)

  // hoisted fragment LDS byte-offsets (loop-invariant).
  // Lane: row = base + (lane&31), global units {2q, 2q+1}, q = lane>>5;
  // stored position of unit u in row r is u ^ ((r>>1)&3).
  const int r31 = lane & 31;
  const int q2  = (lane >> 5) * 2;
  int offA0[2], offA1[2], offB0[2], offB1[2];
#pragma unroll
  for (int ti = 0; ti < 2; ++ti) {
    const int row = wm + ti * 32 + r31;
    const int rot = (row >> 1) & 3;
    offA0[ti] = row * 64 + ((q2    ) ^ rot) * 16;
    offA1[ti] = row * 64 + ((q2 + 1) ^ rot) * 16;
  }
#pragma unroll
  for (int tj = 0; tj < 2; ++tj) {
    const int row = wn + tj * 32 + r31;
    const int rot = (row >> 1) & 3;
    offB0[tj] = row * 64 + ((q2    ) ^ rot) * 16;
    offB1[tj] = row * 64 + ((q2 + 1) ^ rot) * 16;
  }

  // prologue: stage slab 0 into buffer 0
  async_ld16(gA1, &As[0][ldsO1]);
  async_ld16(gA2, &As[0][ldsO2]);
  async_ld16(gB1, &Bs[0][ldsO1]);
  async_ld16(gB2, &Bs[0][ldsO2]);
  gA1 += 64; gA2 += 64; gB1 += 64; gB2 += 64;

#pragma unroll
  for (int kk = 0; kk < DK / 64; ++kk) {
    const int cur = kk & 1;
    // Barrier: (a) drains this wave's vmcnt -> buf[cur] resident (its loads
    // were issued one full iteration ago); (b) all waves done with buf[cur^1].
    __syncthreads();
    if (kk < DK / 64 - 1) {
      const int nxt = cur ^ 1;
      async_ld16(gA1, &As[nxt][ldsO1]);
      async_ld16(gA2, &As[nxt][ldsO2]);
      async_ld16(gB1, &Bs[nxt][ldsO1]);
      async_ld16(gB2, &Bs[nxt][ldsO2]);
      gA1 += 64; gA2 += 64; gB1 += 64; gB2 += 64;
    }

    const char* Ab = As[cur];
    const char* Bb = Bs[cur];
    intx8 a[2], b[2];
#pragma unroll
    for (int ti = 0; ti < 2; ++ti) {
      longx2 lo = *(const longx2*)(Ab + offA0[ti]);
      longx2 hi = *(const longx2*)(Ab + offA1[ti]);
      longx4 t = (longx4){lo.x, lo.y, hi.x, hi.y};
      a[ti] = (intx8)t;
    }
#pragma unroll
    for (int tj = 0; tj < 2; ++tj) {
      longx2 lo = *(const longx2*)(Bb + offB0[tj]);
      longx2 hi = *(const longx2*)(Bb + offB1[tj]);
      longx4 t = (longx4){lo.x, lo.y, hi.x, hi.y};
      b[tj] = (intx8)t;
    }
    // 4 MX-scaled MFMAs, K=64, unit scales (0x7F = 2^0): per-product
    // identical to the non-scaled fp8 path; A and B share the same
    // k-permutation so the contraction is exact (bit-exact since R11).
#pragma unroll
    for (int ti = 0; ti < 2; ++ti)
#pragma unroll
      for (int tj = 0; tj < 2; ++tj)
        acc[ti][tj] = __builtin_amdgcn_mfma_scale_f32_32x32x64_f8f6f4(
            a[ti], b[tj], acc[ti][tj],
            0, 0, 0, 0x7f7f7f7f, 0, 0x7f7f7f7f);
  }

  // epilogue: rowsum[m] += sum_n exp(64 * wf[m][n])
  // C/D 32x32 layout: col = lane&31, row = (reg&3) + 8*(reg>>2) + 4*(lane>>5).
  // 4-level tree: lanes 0/16 (and 32/48) hold 16-col halves of the same
  // row -> both atomicAdd (2-way LDS atomic).
  const int qrow = (lane >> 5) * 4;
#pragma unroll
  for (int ti = 0; ti < 2; ++ti) {
#pragma unroll
    for (int r = 0; r < 16; ++r) {
      float v = __expf(64.0f * acc[ti][0][r]) + __expf(64.0f * acc[ti][1][r]);
      v += __shfl_xor(v, 1, 64);
      v += __shfl_xor(v, 2, 64);
      v += __shfl_xor(v, 4, 64);
      v += __shfl_xor(v, 8, 64);
      if ((lane & 15) == 0)
        atomicAdd(&lsum[wm + ti * 32 + qrow + (r & 3) + 8 * (r >> 2)], v);
    }
  }
  __syncthreads();
  if (tid < 128)
    atomicAdd(&rowsum[tileM + tid], lsum[tid]);
}

// ---- kernel 3: final loss
__global__ void loss_kernel(const float* __restrict__ tgt,
                            const float* __restrict__ rowsum,
                            float* __restrict__ out) {
  __shared__ float wsum[8];
  const int t = threadIdx.x;
  float sum = 0.f;
  const float cM = 0.87758256189037271f;  // cos(0.5)
  const float sM = 0.47942553860420301f;  // sin(0.5)
  for (int i = t; i < BN; i += 512) {
    const float tg_raw = tgt[i];
    const float tg = fminf(fmaxf(tg_raw, -1.f + 1e-7f), 1.f - 1e-7f);
    const float num = 64.f * (tg * cM - sqrtf(fmaxf(1.f - tg * tg, 0.f)) * sM);
    const float den = expf(num) + rowsum[i] - expf(64.f * tg_raw);
    sum += num - logf(den);
  }
#pragma unroll
  for (int off = 1; off < 64; off <<= 1) sum += __shfl_xor(sum, off, 64);
  if ((t & 63) == 0) wsum[t >> 6] = sum;
  __syncthreads();
  if (t == 0) {
    float tot = 0.f;
#pragma unroll
    for (int k = 0; k < 8; ++k) tot += wsum[k];
    out[0] = -tot * (1.0f / (float)BN);
  }
}

extern "C" void kernel_launch(void* const* d_in, const int* in_sizes, int n_in,
                              void* d_out, int out_size, void* d_ws, size_t ws_size,
                              hipStream_t stream) {
  const float* features = (const float*)d_in[0];
  const int*   y_true   = (const int*)d_in[1];
  const float* weight   = (const float*)d_in[2];
  float* out = (float*)d_out;

  char* ws = (char*)d_ws;
  char* wb8    = ws;                          // 16 MB
  char* fb8    = ws + 16777216;               //  1 MB
  float* tgt    = (float*)(ws + 17825792);    //  8 KB
  float* rowsum = (float*)(ws + 17833984);    //  8 KB

  prep_kernel<<<8192 + 512, 256, 0, stream>>>(features, y_true, weight,
                                              (int*)fb8, (int*)wb8, tgt, rowsum);
  gemm_exp_kernel<<<4096, 256, 0, stream>>>(fb8, wb8, rowsum);
  loss_kernel<<<1, 512, 0, stream>>>(tgt, rowsum, out);
}

// Round 6
// 169.652 us; speedup vs baseline: 2.8962x; 1.1335x over previous
//
#include <hip/hip_runtime.h>
#include <hip/hip_bf16.h>
#include <math.h>

// ArcFace loss, MI355X. B=2048, D=512, C=32768.
// R14: MX-scaled fp8 GEMM (mfma_scale_f32_32x32x64_f8f6f4, unit scales
// 0x7F = 2^0; layouts bit-exact since R11). R13 killed the spill but ran
// at 2 waves/SIMD (192 regs/wave: acc 64 + vgpr 124) -> MfmaUtil 13%,
// latency-bound (MFMA busy time == 14.7us pipe floor; kernel 98.8us).
// R14 restructures for TLP: per-wave output 32x64 (acc 32, operands 24
// -> ~105 regs/wave -> 4 waves/SIMD), 512-thr blocks (8 waves, 4Mx2N) on
// the same 128x128 tile, 2 blocks/CU (two independent barrier groups/CU),
// BK=128 per barrier (two 64-slabs: 4 MFMAs + 12 ds_reads per wave per
// barrier, half the barriers, prefetch gets a full BK-128 compute phase).
// launch_bounds(512,4) caps at 128 regs: arch half ~96 >= ~75 live ->
// no spill (R11-R13 lesson: spill <=> arch-need > cap - acc).
// Staging/XOR-rotation/ping-pong/prep/loss unchanged.

#define BN 2048
#define DK 512
#define CN 32768

typedef __attribute__((ext_vector_type(4))) float floatx4;
typedef __attribute__((ext_vector_type(16))) float floatx16;
typedef __attribute__((ext_vector_type(2))) long longx2;
typedef __attribute__((ext_vector_type(4))) long longx4;
typedef __attribute__((ext_vector_type(8))) int intx8;

__device__ inline float dot4(floatx4 a, floatx4 b) {
  return a.x * b.x + a.y * b.y + a.z * b.z + a.w * b.w;
}

__device__ inline int pack_fp8x4(floatx4 v) {
  int r = __builtin_amdgcn_cvt_pk_fp8_f32(v.x, v.y, 0, false);
  r = __builtin_amdgcn_cvt_pk_fp8_f32(v.z, v.w, r, true);
  return r;
}

// dword j (0..15) of a 64B slab -> MFMA-ready position:
// q=(j>>1)&3 (8B piece), p=j>>3 (k-step), dest = q*4 + p*2 + (j&1)
__device__ inline int permute16(int j) {
  return ((j >> 1) & 3) * 4 + (j >> 3) * 2 + (j & 1);
}

__device__ inline void async_ld16(const void* g, void* l) {
  __builtin_amdgcn_global_load_lds(
      (const __attribute__((address_space(1))) void*)g,
      (__attribute__((address_space(3))) void*)l, 16, 0, 0);
}

// ---- kernel 1: fused prep -> fp8 rows (512 B each), MFMA-ready byte order.
__global__ void prep_kernel(const float* __restrict__ feat,
                            const int* __restrict__ y,
                            const float* __restrict__ w,
                            int* __restrict__ fb8,     // [BN][128] dwords
                            int* __restrict__ wb8,     // [CN][128] dwords
                            float* __restrict__ tgt,
                            float* __restrict__ rowsum) {
  const int wave = threadIdx.x >> 6;
  const int l = threadIdx.x & 63;
  const int d0 = ((l >> 4) * 16)       + permute16(l & 15);
  const int d1 = ((4 + (l >> 4)) * 16) + permute16(l & 15);
  if (blockIdx.x < 8192) {
    const int row = blockIdx.x * 4 + wave;
    const floatx4* src = (const floatx4*)(w + (size_t)row * DK);
    floatx4 v0 = src[l];
    floatx4 v1 = src[64 + l];
    float s = dot4(v0, v0) + dot4(v1, v1);
#pragma unroll
    for (int off = 1; off < 64; off <<= 1) s += __shfl_xor(s, off, 64);
    const float scale = 1.0f / fmaxf(sqrtf(s), 1e-12f);
    v0 *= scale; v1 *= scale;
    int* db = wb8 + (size_t)row * 128;
    db[d0] = pack_fp8x4(v0);
    db[d1] = pack_fp8x4(v1);
  } else {
    const int i = (blockIdx.x - 8192) * 4 + wave;
    const floatx4* src = (const floatx4*)(feat + (size_t)i * DK);
    floatx4 v0 = src[l];
    floatx4 v1 = src[64 + l];
    const int cls = y[i];
    const floatx4* wr = (const floatx4*)(w + (size_t)cls * DK);
    floatx4 w0 = wr[l], w1 = wr[64 + l];
    float s  = dot4(v0, v0) + dot4(v1, v1);
    float d  = dot4(v0, w0) + dot4(v1, w1);
    float wn = dot4(w0, w0) + dot4(w1, w1);
#pragma unroll
    for (int off = 1; off < 64; off <<= 1) {
      s  += __shfl_xor(s, off, 64);
      d  += __shfl_xor(d, off, 64);
      wn += __shfl_xor(wn, off, 64);
    }
    const float fscale = 1.0f / fmaxf(sqrtf(s), 1e-12f);
    v0 *= fscale; v1 *= fscale;
    int* db = fb8 + (size_t)i * 128;
    db[d0] = pack_fp8x4(v0);
    db[d1] = pack_fp8x4(v1);
    if (l == 0) {
      tgt[i] = d * fscale / fmaxf(sqrtf(wn), 1e-12f);
      rowsum[i] = 0.0f;
    }
  }
}

// ---- kernel 2: 128(M)x128(N) MX-fp8 MFMA GEMM (32x32x64, unit scales),
// 512 threads (8 waves, 4Mx2N, 32x64 per wave), BK=128 per barrier
// (2 slabs), ping-pong LDS, fused exp row-sum.
__launch_bounds__(512, 4)
__global__ void gemm_exp_kernel(const char* __restrict__ fb8,   // [BN][512] B
                                const char* __restrict__ wb8,   // [CN][512] B
                                float* __restrict__ rowsum) {
  __shared__ char As[2][2 * 128 * 64];   // 2 bufs x 2 slabs x 8 KB = 32 KB
  __shared__ char Bs[2][2 * 128 * 64];   // 32 KB
  __shared__ float lsum[128];

  const int tid  = threadIdx.x;
  const int wave = tid >> 6;
  const int lane = tid & 63;

  // XCD swizzle: n bits {b11..b7}=Ngroup, {b6..b3}=M-tile, {b2..b0}=xcd.
  // N-tile = Ngroup*8 + xcd, so XCD x owns N-tiles == x (mod 8): bijective.
  const int n = blockIdx.x;
  const int tileM = ((n >> 3) & 15) * 128;
  const int tileN = (((n >> 7) << 3) | (n & 7)) * 128;

  const int wm = (wave & 3) * 32;   // wave M offset (0..96)
  const int wn = (wave >> 2) * 64;  // wave N offset (0 or 64)

  if (tid < 128) lsum[tid] = 0.0f;  // covered by first K-loop barrier

  floatx16 acc[2];
#pragma unroll
  for (int tj = 0; tj < 2; ++tj)
#pragma unroll
    for (int r = 0; r < 16; ++r)
      acc[tj][r] = 0.0f;

  // staging: per BK-128 iteration, A needs 2 slabs x 512 chunks of 16 B;
  // thread t stages chunk t of slab lo (LDS byte t*16) and chunk t of slab
  // hi (LDS byte 8192 + t*16); same for B. Chunk c -> row c>>2, stored pos
  // c&3, fetched global unit (c&3)^((row>>1)&3). LDS dest passed as
  // wave-uniform base (wave*1024); HW adds lane*16.
  const int rowL = tid >> 2;                         // rows 0..127
  const int uL   = (tid & 3) ^ ((rowL >> 1) & 3);
  const char* gA = fb8 + (size_t)(tileM + rowL) * DK + uL * 16;
  const char* gB = wb8 + (size_t)(tileN + rowL) * DK + uL * 16;
  const int ldsO = wave * 1024;   // wave-uniform; lane*16 added by HW

  // hoisted fragment LDS byte-offsets (slab-local, loop-invariant).
  // Lane: row = base + (lane&31), global units {2q, 2q+1}, q = lane>>5;
  // stored position of unit u in row r is u ^ ((r>>1)&3).
  const int r31 = lane & 31;
  const int q2  = (lane >> 5) * 2;
  int offA0, offA1, offB0[2], offB1[2];
  {
    const int row = wm + r31;
    const int rot = (row >> 1) & 3;
    offA0 = row * 64 + ((q2    ) ^ rot) * 16;
    offA1 = row * 64 + ((q2 + 1) ^ rot) * 16;
  }
#pragma unroll
  for (int tj = 0; tj < 2; ++tj) {
    const int row = wn + tj * 32 + r31;
    const int rot = (row >> 1) & 3;
    offB0[tj] = row * 64 + ((q2    ) ^ rot) * 16;
    offB1[tj] = row * 64 + ((q2 + 1) ^ rot) * 16;
  }

  // prologue: stage iteration 0 (slabs 0,1) into buffer 0
  async_ld16(gA,      &As[0][ldsO]);
  async_ld16(gA + 64, &As[0][8192 + ldsO]);
  async_ld16(gB,      &Bs[0][ldsO]);
  async_ld16(gB + 64, &Bs[0][8192 + ldsO]);
  gA += 128; gB += 128;

#pragma unroll
  for (int it = 0; it < DK / 128; ++it) {
    const int cur = it & 1;
    // Barrier: (a) drains this wave's vmcnt -> buf[cur] resident (its loads
    // were issued one full BK-128 iteration ago); (b) all waves done with
    // buf[cur^1].
    __syncthreads();
    if (it < DK / 128 - 1) {
      const int nxt = cur ^ 1;
      async_ld16(gA,      &As[nxt][ldsO]);
      async_ld16(gA + 64, &As[nxt][8192 + ldsO]);
      async_ld16(gB,      &Bs[nxt][ldsO]);
      async_ld16(gB + 64, &Bs[nxt][8192 + ldsO]);
      gA += 128; gB += 128;
    }

#pragma unroll
    for (int ks = 0; ks < 2; ++ks) {
      const char* Ab = &As[cur][ks * 8192];
      const char* Bb = &Bs[cur][ks * 8192];
      intx8 a, b[2];
      {
        longx2 lo = *(const longx2*)(Ab + offA0);
        longx2 hi = *(const longx2*)(Ab + offA1);
        a = (intx8)(longx4){lo.x, lo.y, hi.x, hi.y};
      }
#pragma unroll
      for (int tj = 0; tj < 2; ++tj) {
        longx2 lo = *(const longx2*)(Bb + offB0[tj]);
        longx2 hi = *(const longx2*)(Bb + offB1[tj]);
        b[tj] = (intx8)(longx4){lo.x, lo.y, hi.x, hi.y};
      }
      // 2 MX-scaled MFMAs, K=64, unit scales (0x7F = 2^0): per-product
      // identical to the non-scaled fp8 path; A and B share the same
      // k-permutation so the contraction is exact (bit-exact since R11).
#pragma unroll
      for (int tj = 0; tj < 2; ++tj)
        acc[tj] = __builtin_amdgcn_mfma_scale_f32_32x32x64_f8f6f4(
            a, b[tj], acc[tj],
            0, 0, 0, 0x7f7f7f7f, 0, 0x7f7f7f7f);
    }
  }

  // epilogue: rowsum[m] += sum_n exp(64 * wf[m][n])
  // C/D 32x32 layout: col = lane&31, row = (reg&3) + 8*(reg>>2) + 4*(lane>>5).
  // Row-reduce across the 32 columns (lanes within each 32-half), then one
  // atomic per half (distinct rows for lane 0 vs lane 32). Waves w and w+4
  // share wm (different N-halves) -> 2-way atomic per lsum row.
  const int qrow = (lane >> 5) * 4;
#pragma unroll
  for (int r = 0; r < 16; ++r) {
    float v = __expf(64.0f * acc[0][r]) + __expf(64.0f * acc[1][r]);
    v += __shfl_xor(v, 1, 64);
    v += __shfl_xor(v, 2, 64);
    v += __shfl_xor(v, 4, 64);
    v += __shfl_xor(v, 8, 64);
    v += __shfl_xor(v, 16, 64);
    if ((lane & 31) == 0)
      atomicAdd(&lsum[wm + qrow + (r & 3) + 8 * (r >> 2)], v);
  }
  __syncthreads();
  if (tid < 128)
    atomicAdd(&rowsum[tileM + tid], lsum[tid]);
}

// ---- kernel 3: final loss
__global__ void loss_kernel(const float* __restrict__ tgt,
                            const float* __restrict__ rowsum,
                            float* __restrict__ out) {
  __shared__ float wsum[8];
  const int t = threadIdx.x;
  float sum = 0.f;
  const float cM = 0.87758256189037271f;  // cos(0.5)
  const float sM = 0.47942553860420301f;  // sin(0.5)
  for (int i = t; i < BN; i += 512) {
    const float tg_raw = tgt[i];
    const float tg = fminf(fmaxf(tg_raw, -1.f + 1e-7f), 1.f - 1e-7f);
    const float num = 64.f * (tg * cM - sqrtf(fmaxf(1.f - tg * tg, 0.f)) * sM);
    const float den = expf(num) + rowsum[i] - expf(64.f * tg_raw);
    sum += num - logf(den);
  }
#pragma unroll
  for (int off = 1; off < 64; off <<= 1) sum += __shfl_xor(sum, off, 64);
  if ((t & 63) == 0) wsum[t >> 6] = sum;
  __syncthreads();
  if (t == 0) {
    float tot = 0.f;
#pragma unroll
    for (int k = 0; k < 8; ++k) tot += wsum[k];
    out[0] = -tot * (1.0f / (float)BN);
  }
}

extern "C" void kernel_launch(void* const* d_in, const int* in_sizes, int n_in,
                              void* d_out, int out_size, void* d_ws, size_t ws_size,
                              hipStream_t stream) {
  const float* features = (const float*)d_in[0];
  const int*   y_true   = (const int*)d_in[1];
  const float* weight   = (const float*)d_in[2];
  float* out = (float*)d_out;

  char* ws = (char*)d_ws;
  char* wb8    = ws;                          // 16 MB
  char* fb8    = ws + 16777216;               //  1 MB
  float* tgt    = (float*)(ws + 17825792);    //  8 KB
  float* rowsum = (float*)(ws + 17833984);    //  8 KB

  prep_kernel<<<8192 + 512, 256, 0, stream>>>(features, y_true, weight,
                                              (int*)fb8, (int*)wb8, tgt, rowsum);
  gemm_exp_kernel<<<4096, 512, 0, stream>>>(fb8, wb8, rowsum);
  loss_kernel<<<1, 512, 0, stream>>>(tgt, rowsum, out);
}